// Round 2
// baseline (102.171 us; speedup 1.0000x reference)
//
#include <hip/hip_runtime.h>
#include <hip/hip_bf16.h>

// Problem geometry (fixed by the reference)
constexpr int HH = 4096;          // image height
constexpr int WW = 4096;          // image width
constexpr int NB = 1048576;       // total 4x4 blocks (BY*BX), BX=1024

#define L2E 1.4426950408889634f

__device__ __forceinline__ float fexp2(float x) { return __builtin_amdgcn_exp2f(x); }
__device__ __forceinline__ float frcp(float x)  { return __builtin_amdgcn_rcpf(x); }
// sigmoid(x) = 1/(1+e^-x) = rcp(1 + 2^(-x*log2e)) : 2 VALU + 2 TRANS
__device__ __forceinline__ float fsigmoid(float x) {
    return frcp(1.0f + fexp2(-x * L2E));
}

__global__ __launch_bounds__(256) void bc6_decode_kernel(
    const float* __restrict__ endpoints,   // (NB,4,3)
    const float* __restrict__ indices,     // (NB,16)
    const float* __restrict__ logits,      // (NB,32)
    const float* __restrict__ bank,        // (32,16) 0/1
    float* __restrict__ out)               // (3,H,W)
{
    // partition bank rows as float4 -> ds_read_b128 uniform-address broadcast
    __shared__ float4 s_bank[32][4];
    const int tid = threadIdx.x;
    if (tid < 128) {
        reinterpret_cast<float4*>(s_bank)[tid] =
            reinterpret_cast<const float4*>(bank)[tid];
    }
    __syncthreads();

    const int b = blockIdx.x * 256 + tid;   // one thread per BC block

    // ---- fused: softmax numerators + (p @ bank) matvec -------------------
    // No max-subtraction (logits ~N(0,1), exp2 arg bounded ~ +-8): saves the
    // 31-op max tree + 32 subs. Normalization folded in after the matvec.
    float mk[16];
    #pragma unroll
    for (int j = 0; j < 16; ++j) mk[j] = 0.0f;
    float esum = 0.0f;
    {
        const float4* lp = reinterpret_cast<const float4*>(logits) + (size_t)b * 8;
        #pragma unroll
        for (int q = 0; q < 8; ++q) {
            const float4 v = lp[q];
            const float ex[4] = { fexp2(v.x * L2E), fexp2(v.y * L2E),
                                  fexp2(v.z * L2E), fexp2(v.w * L2E) };
            #pragma unroll
            for (int t = 0; t < 4; ++t) {
                const int k = q * 4 + t;
                const float e = ex[t];
                esum += e;
                const float4 r0 = s_bank[k][0];
                const float4 r1 = s_bank[k][1];
                const float4 r2 = s_bank[k][2];
                const float4 r3 = s_bank[k][3];
                mk[ 0] = fmaf(e, r0.x, mk[ 0]);
                mk[ 1] = fmaf(e, r0.y, mk[ 1]);
                mk[ 2] = fmaf(e, r0.z, mk[ 2]);
                mk[ 3] = fmaf(e, r0.w, mk[ 3]);
                mk[ 4] = fmaf(e, r1.x, mk[ 4]);
                mk[ 5] = fmaf(e, r1.y, mk[ 5]);
                mk[ 6] = fmaf(e, r1.z, mk[ 6]);
                mk[ 7] = fmaf(e, r1.w, mk[ 7]);
                mk[ 8] = fmaf(e, r2.x, mk[ 8]);
                mk[ 9] = fmaf(e, r2.y, mk[ 9]);
                mk[10] = fmaf(e, r2.z, mk[10]);
                mk[11] = fmaf(e, r2.w, mk[11]);
                mk[12] = fmaf(e, r3.x, mk[12]);
                mk[13] = fmaf(e, r3.y, mk[13]);
                mk[14] = fmaf(e, r3.z, mk[14]);
                mk[15] = fmaf(e, r3.w, mk[15]);
            }
        }
    }
    {
        const float inv = frcp(esum);
        #pragma unroll
        for (int j = 0; j < 16; ++j) mk[j] *= inv;
    }

    // ---- indices -> w64 in [0,64] ----------------------------------------
    // Mode-10 LUT [0,9,18,27,37,46,55,64] is piecewise linear:
    //   w*64 = 9*xs + clamp(xs-3, 0, 1),  xs = sigmoid(x)*7
    // (exactly equals lut[x0]*(1-f)+lut[x1]*f on every segment)
    float w64[16];
    {
        const float4* ip = reinterpret_cast<const float4*>(indices) + (size_t)b * 4;
        #pragma unroll
        for (int q = 0; q < 4; ++q) {
            const float4 v = ip[q];
            const float x4[4] = { v.x, v.y, v.z, v.w };
            #pragma unroll
            for (int t = 0; t < 4; ++t) {
                const float xs = fsigmoid(x4[t]) * 7.0f;
                const float c  = fminf(fmaxf(xs - 3.0f, 0.0f), 1.0f);
                w64[q*4 + t] = fmaf(9.0f, xs, c);
            }
        }
    }

    // ---- endpoints: e_u = 31248*sigmoid + 248 -----------------------------
    // ((sig*63*65536+32768)/64)*(31/64) == 31248*sig + 248 exactly in algebra
    float s[12];
    {
        const float4* ep = reinterpret_cast<const float4*>(endpoints) + (size_t)b * 3;
        const float4 v0 = ep[0];
        const float4 v1 = ep[1];
        const float4 v2 = ep[2];
        s[0] = fsigmoid(v0.x); s[1]  = fsigmoid(v0.y); s[2]  = fsigmoid(v0.z);
        s[3] = fsigmoid(v0.w); s[4]  = fsigmoid(v1.x); s[5]  = fsigmoid(v1.y);
        s[6] = fsigmoid(v1.z); s[7]  = fsigmoid(v1.w); s[8]  = fsigmoid(v2.x);
        s[9] = fsigmoid(v2.y); s[10] = fsigmoid(v2.z); s[11] = fsigmoid(v2.w);
    }

    // ---- decode + store ---------------------------------------------------
    const int by = b >> 10;
    const int bx = b & 1023;
    float* const obase = out + (size_t)(by * 4) * WW + (size_t)(bx * 4);

    #pragma unroll
    for (int c = 0; c < 3; ++c) {
        const float sA = s[c], sB = s[3 + c], sC = s[6 + c], sD = s[9 + c];
        const float euA = fmaf(31248.0f, sA, 248.0f);
        const float euC = fmaf(31248.0f, sC, 248.0f);
        const float dBA = 488.25f * (sB - sA);       // (euB-euA)/64
        const float dDC = 488.25f * (sD - sC);       // (euD-euC)/64
        const float dAC = euA - euC;                 // y1-y2 constant part
        const float dd  = dBA - dDC;                 // y1-y2 w-slope
        float* const cbase = obase + (size_t)c * (HH * (size_t)WW);
        #pragma unroll
        for (int py = 0; py < 4; ++py) {
            float o4[4];
            #pragma unroll
            for (int px = 0; px < 4; ++px) {
                const int j = py * 4 + px;
                const float w  = w64[j];
                const float t  = fmaf(w, dd,  dAC);     // y1 - y2
                const float y2 = fmaf(w, dDC, euC);
                const float y  = fmaf(mk[j], t, y2);
                // hh = clamp(floor((y-1)/1024) - 1, 0, 31)
                const float tf = fmaf(y, 9.765625e-4f, -9.765625e-4f);
                const float hh = fminf(fmaxf(floorf(tf) - 1.0f, 0.0f), 31.0f);
                // out = 2^(hh-14) * (y/1024 - hh)
                const float mant = fmaf(y, 9.765625e-4f, -hh);
                o4[px] = fexp2(hh - 14.0f) * mant;
            }
            *reinterpret_cast<float4*>(cbase + (size_t)py * WW) =
                make_float4(o4[0], o4[1], o4[2], o4[3]);
        }
    }
}

extern "C" void kernel_launch(void* const* d_in, const int* in_sizes, int n_in,
                              void* d_out, int out_size, void* d_ws, size_t ws_size,
                              hipStream_t stream) {
    const float* endpoints = (const float*)d_in[0];
    const float* indices   = (const float*)d_in[1];
    const float* logits    = (const float*)d_in[2];
    const float* bank      = (const float*)d_in[3];
    // d_in[4] (weight_lut) folded into closed form: [0,9,18,27,37,46,55,64]/64
    float* out             = (float*)d_out;

    const int threads = 256;
    const int blocks  = NB / threads;   // 4096
    bc6_decode_kernel<<<blocks, threads, 0, stream>>>(
        endpoints, indices, logits, bank, out);
}

// Round 4
// 74.344 us; speedup vs baseline: 1.3743x; 1.3743x over previous
//
#include <hip/hip_runtime.h>
#include <hip/hip_bf16.h>

// Problem geometry (fixed by the reference)
constexpr int HH = 4096;          // image height
constexpr int WW = 4096;          // image width
constexpr int NB = 1048576;       // total 4x4 blocks (BY*BX), BX=1024

#define L2E 1.4426950408889634f

// native vector type for __builtin_nontemporal_store (HIP float4 is rejected)
typedef float vfloat4 __attribute__((ext_vector_type(4)));

__device__ __forceinline__ float fexp2(float x) { return __builtin_amdgcn_exp2f(x); }
__device__ __forceinline__ float frcp(float x)  { return __builtin_amdgcn_rcpf(x); }
// sigmoid(x) = 1/(1+e^-x) = rcp(1 + 2^(-x*log2e))
__device__ __forceinline__ float fsigmoid(float x) {
    return frcp(1.0f + fexp2(-x * L2E));
}

__global__ __launch_bounds__(256, 4) void bc6_decode_kernel(
    const float* __restrict__ endpoints,   // (NB,4,3)
    const float* __restrict__ indices,     // (NB,16)
    const float* __restrict__ logits,      // (NB,32)
    const float* __restrict__ bank,        // (32,16) 0/1
    float* __restrict__ out)               // (3,H,W)
{
    // partition bank rows as float4 -> ds_read_b128 uniform-address broadcast
    __shared__ float4 s_bank[32][4];
    const int tid = threadIdx.x;
    if (tid < 128) {
        reinterpret_cast<float4*>(s_bank)[tid] =
            reinterpret_cast<const float4*>(bank)[tid];
    }
    __syncthreads();

    const int b = blockIdx.x * 256 + tid;   // one thread per BC block

    // ---- hoist ALL global loads: 15 float4 in flight before any compute ----
    const float4* lp = reinterpret_cast<const float4*>(logits)    + (size_t)b * 8;
    const float4* ip = reinterpret_cast<const float4*>(indices)   + (size_t)b * 4;
    const float4* ep = reinterpret_cast<const float4*>(endpoints) + (size_t)b * 3;
    float4 L[8], I[4], E[3];
    #pragma unroll
    for (int q = 0; q < 8; ++q) L[q] = lp[q];   // consumed first -> issued first
    #pragma unroll
    for (int q = 0; q < 4; ++q) I[q] = ip[q];
    #pragma unroll
    for (int q = 0; q < 3; ++q) E[q] = ep[q];
    // Pin the loads above all compute so the scheduler can't sink them.
    __builtin_amdgcn_sched_barrier(0);

    // ---- fused: softmax numerators + (p @ bank) matvec ---------------------
    float mk[16];
    #pragma unroll
    for (int j = 0; j < 16; ++j) mk[j] = 0.0f;
    float esum = 0.0f;
    #pragma unroll
    for (int q = 0; q < 8; ++q) {
        const float4 v = L[q];
        const float ex[4] = { fexp2(v.x * L2E), fexp2(v.y * L2E),
                              fexp2(v.z * L2E), fexp2(v.w * L2E) };
        #pragma unroll
        for (int t = 0; t < 4; ++t) {
            const int k = q * 4 + t;
            const float e = ex[t];
            esum += e;
            const float4 r0 = s_bank[k][0];
            const float4 r1 = s_bank[k][1];
            const float4 r2 = s_bank[k][2];
            const float4 r3 = s_bank[k][3];
            mk[ 0] = fmaf(e, r0.x, mk[ 0]);
            mk[ 1] = fmaf(e, r0.y, mk[ 1]);
            mk[ 2] = fmaf(e, r0.z, mk[ 2]);
            mk[ 3] = fmaf(e, r0.w, mk[ 3]);
            mk[ 4] = fmaf(e, r1.x, mk[ 4]);
            mk[ 5] = fmaf(e, r1.y, mk[ 5]);
            mk[ 6] = fmaf(e, r1.z, mk[ 6]);
            mk[ 7] = fmaf(e, r1.w, mk[ 7]);
            mk[ 8] = fmaf(e, r2.x, mk[ 8]);
            mk[ 9] = fmaf(e, r2.y, mk[ 9]);
            mk[10] = fmaf(e, r2.z, mk[10]);
            mk[11] = fmaf(e, r2.w, mk[11]);
            mk[12] = fmaf(e, r3.x, mk[12]);
            mk[13] = fmaf(e, r3.y, mk[13]);
            mk[14] = fmaf(e, r3.z, mk[14]);
            mk[15] = fmaf(e, r3.w, mk[15]);
        }
    }
    {
        const float inv = frcp(esum);
        #pragma unroll
        for (int j = 0; j < 16; ++j) mk[j] *= inv;
    }

    // ---- indices -> w64 in [0,64] ------------------------------------------
    // Mode-10 LUT [0,9,18,27,37,46,55,64] is piecewise linear:
    //   w*64 = 9*xs + clamp(xs-3, 0, 1),  xs = sigmoid(x)*7
    float w64[16];
    #pragma unroll
    for (int q = 0; q < 4; ++q) {
        const float4 v = I[q];
        const float x4[4] = { v.x, v.y, v.z, v.w };
        #pragma unroll
        for (int t = 0; t < 4; ++t) {
            const float xs = fsigmoid(x4[t]) * 7.0f;
            const float c  = fminf(fmaxf(xs - 3.0f, 0.0f), 1.0f);
            w64[q*4 + t] = fmaf(9.0f, xs, c);
        }
    }

    // ---- endpoints: e_u = 31248*sigmoid + 248 --------------------------------
    float s[12];
    {
        s[0] = fsigmoid(E[0].x); s[1]  = fsigmoid(E[0].y); s[2]  = fsigmoid(E[0].z);
        s[3] = fsigmoid(E[0].w); s[4]  = fsigmoid(E[1].x); s[5]  = fsigmoid(E[1].y);
        s[6] = fsigmoid(E[1].z); s[7]  = fsigmoid(E[1].w); s[8]  = fsigmoid(E[2].x);
        s[9] = fsigmoid(E[2].y); s[10] = fsigmoid(E[2].z); s[11] = fsigmoid(E[2].w);
    }

    // ---- decode + store (non-temporal: output never re-read) ----------------
    const int by = b >> 10;
    const int bx = b & 1023;
    float* const obase = out + (size_t)(by * 4) * WW + (size_t)(bx * 4);

    #pragma unroll
    for (int c = 0; c < 3; ++c) {
        const float sA = s[c], sB = s[3 + c], sC = s[6 + c], sD = s[9 + c];
        const float euA = fmaf(31248.0f, sA, 248.0f);
        const float euC = fmaf(31248.0f, sC, 248.0f);
        const float dBA = 488.25f * (sB - sA);       // (euB-euA)/64
        const float dDC = 488.25f * (sD - sC);       // (euD-euC)/64
        const float dAC = euA - euC;                 // y1-y2 constant part
        const float dd  = dBA - dDC;                 // y1-y2 w-slope
        float* const cbase = obase + (size_t)c * (HH * (size_t)WW);
        #pragma unroll
        for (int py = 0; py < 4; ++py) {
            vfloat4 o4;
            #pragma unroll
            for (int px = 0; px < 4; ++px) {
                const int j = py * 4 + px;
                const float w  = w64[j];
                const float t  = fmaf(w, dd,  dAC);     // y1 - y2
                const float y2 = fmaf(w, dDC, euC);
                const float y  = fmaf(mk[j], t, y2);
                // hh = clamp(floor((y-1)/1024) - 1, 0, 31)
                const float tf = fmaf(y, 9.765625e-4f, -9.765625e-4f);
                const float hh = fminf(fmaxf(floorf(tf) - 1.0f, 0.0f), 31.0f);
                // out = 2^(hh-14) * (y/1024 - hh)
                const float mant = fmaf(y, 9.765625e-4f, -hh);
                o4[px] = fexp2(hh - 14.0f) * mant;
            }
            __builtin_nontemporal_store(
                o4, reinterpret_cast<vfloat4*>(cbase + (size_t)py * WW));
        }
    }
}

extern "C" void kernel_launch(void* const* d_in, const int* in_sizes, int n_in,
                              void* d_out, int out_size, void* d_ws, size_t ws_size,
                              hipStream_t stream) {
    const float* endpoints = (const float*)d_in[0];
    const float* indices   = (const float*)d_in[1];
    const float* logits    = (const float*)d_in[2];
    const float* bank      = (const float*)d_in[3];
    // d_in[4] (weight_lut) folded into closed form: [0,9,18,27,37,46,55,64]/64
    float* out             = (float*)d_out;

    const int threads = 256;
    const int blocks  = NB / threads;   // 4096
    bc6_decode_kernel<<<blocks, threads, 0, stream>>>(
        endpoints, indices, logits, bank, out);
}